// Round 5
// baseline (89.072 us; speedup 1.0000x reference)
//
#include <hip/hip_runtime.h>

// Problem constants: B=32, L1=L2=64, DIM_HID=256, FEAT=512
#define BB 32
#define LL 64
#define HH 256
#define FF 512
#define WSTRIDE 1024   // W is [256, 1024] row-major
#define HT 16          // h-tile per block: 512 blocks = 2/CU
#define YSTR 17        // f32 y-tile stride (16 + 1 pad)

typedef float float4v __attribute__((ext_vector_type(4)));
typedef short short8  __attribute__((ext_vector_type(8)));

// Packed fp32x2 -> bf16x2 (RNE in HW). No builtin on gfx950 -> inline asm.
static __device__ __forceinline__ unsigned int cvt_pk_bf16(float lo, float hi) {
    unsigned int r;
    asm("v_cvt_pk_bf16_f32 %0, %1, %2" : "=v"(r) : "v"(lo), "v"(hi));
    return r;
}

// 8 fp32 (two float4) -> short8 bf16
static __device__ __forceinline__ short8 cvt8(float4 lo, float4 hi) {
    union { short8 s; unsigned int u[4]; } o;
    o.u[0] = cvt_pk_bf16(lo.x, lo.y);
    o.u[1] = cvt_pk_bf16(lo.z, lo.w);
    o.u[2] = cvt_pk_bf16(hi.x, hi.y);
    o.u[3] = cvt_pk_bf16(hi.z, hi.w);
    return o.s;
}

// ---------------- Single fused kernel, NO LDS staging ----------------
// Working set (~9 MB) is L2/L3-resident; MFMA 16x16x32 fragments are 8
// CONTIGUOUS elements along K for both A and B (lane&15 = row, (lane>>4)*8
// = k-offset) -> every fragment is one aligned 32B global fp32 load.
// So: load fragments straight from global, cvt to bf16 in-register,
// MFMA. Zero barriers in the K-loop; the compiler pipelines the 96
// independent loads per thread. LDS only for the tiny epilogue tiles.
// A-reuse stays XCD-local: the 16 h-blocks of batch b all have linear
// block id == b (mod 8) -> same XCD L2.
__global__ __launch_bounds__(256)
void fused_kernel(const float* __restrict__ x1,
                  const float* __restrict__ x2,
                  const float* __restrict__ W,
                  const int* __restrict__ s1p,
                  const int* __restrict__ s2p,
                  const float* __restrict__ bias,
                  float* __restrict__ out) {
    const int b  = blockIdx.x;
    const int h0 = blockIdx.y * HT;

    __shared__ float y1t[LL][YSTR];        // 4352 B
    __shared__ float y2t[LL][YSTR];        // 4352 B
    __shared__ float partial[16][YSTR];    // 1088 B

    const int t      = threadIdx.x;
    const int lane   = t & 63;
    const int wid    = t >> 6;          // 0..3
    const int srcSel = wid >> 1;        // 0: y1 (x1,W-left), 1: y2 (x2,W-right)
    const int mrow   = (wid & 1) * 32;  // wave's 32-row half
    const int lm     = lane & 15;
    const int quad   = lane >> 4;

    // fragment row pointers (k-offset quad*8 folded in)
    const float* Xsrc = srcSel ? x2 : x1;
    const float* aRow0 = Xsrc + (size_t)(b * LL + mrow + lm) * FF + quad * 8;
    const float* aRow1 = aRow0 + (size_t)16 * FF;
    const float* bRow  = W + (size_t)(h0 + lm) * WSTRIDE + srcSel * FF + quad * 8;

    float4v acc[2];
    acc[0] = (float4v){0.f, 0.f, 0.f, 0.f};
    acc[1] = (float4v){0.f, 0.f, 0.f, 0.f};

    // K-loop: 16 steps of K=32; k = kt*32 + quad*8 (+0..7) per fragment.
    // No synchronization; unroll 4 bounds in-flight registers (~24 float4).
    #pragma unroll 4
    for (int kt = 0; kt < FF / 32; ++kt) {
        const int k = kt * 32;
        const float4 a0lo = *(const float4*)(aRow0 + k);
        const float4 a0hi = *(const float4*)(aRow0 + k + 4);
        const float4 a1lo = *(const float4*)(aRow1 + k);
        const float4 a1hi = *(const float4*)(aRow1 + k + 4);
        const float4 blo  = *(const float4*)(bRow + k);
        const float4 bhi  = *(const float4*)(bRow + k + 4);
        const short8 a0 = cvt8(a0lo, a0hi);
        const short8 a1 = cvt8(a1lo, a1hi);
        const short8 b0 = cvt8(blo, bhi);
        acc[0] = __builtin_amdgcn_mfma_f32_16x16x32_bf16(a0, b0, acc[0], 0, 0, 0);
        acc[1] = __builtin_amdgcn_mfma_f32_16x16x32_bf16(a1, b0, acc[1], 0, 0, 0);
    }

    // epilogue -> LDS y-tiles; fold bias into y2'
    // C/D layout: col = lane&15, row = quad*4 + j (m89-verified)
    {
        float (*yt)[YSTR] = srcSel ? y2t : y1t;
        const float bv = srcSel ? bias[h0 + lm] : 0.0f;
        #pragma unroll
        for (int im = 0; im < 2; ++im)
            #pragma unroll
            for (int j = 0; j < 4; ++j)
                yt[mrow + im * 16 + quad * 4 + j][lm] = acc[im][j] + bv;
    }
    __syncthreads();

    // masked pair relu-sum: thread = (h in 0..15, i-chunk of 4)
    const int n1 = s1p[b];
    const int n2 = s2p[b];
    const int h  = t & 15;
    const int ic = t >> 4;   // 0..15

    float r1[4];
    #pragma unroll
    for (int ii = 0; ii < 4; ++ii) {
        const int i = ic * 4 + ii;
        r1[ii] = (i < n1) ? y1t[i][h] : -1e30f;  // invalid i -> relu gives 0
    }

    float ac[4] = {0.f, 0.f, 0.f, 0.f};
    int j = 0;
    for (; j + 4 <= n2; j += 4) {
        const float v0 = y2t[j][h];
        const float v1 = y2t[j + 1][h];
        const float v2 = y2t[j + 2][h];
        const float v3 = y2t[j + 3][h];
        #pragma unroll
        for (int ii = 0; ii < 4; ++ii) {
            ac[ii] += fmaxf(r1[ii] + v0, 0.f);
            ac[ii] += fmaxf(r1[ii] + v1, 0.f);
            ac[ii] += fmaxf(r1[ii] + v2, 0.f);
            ac[ii] += fmaxf(r1[ii] + v3, 0.f);
        }
    }
    for (; j < n2; ++j) {
        const float v0 = y2t[j][h];
        #pragma unroll
        for (int ii = 0; ii < 4; ++ii)
            ac[ii] += fmaxf(r1[ii] + v0, 0.f);
    }
    partial[ic][h] = (ac[0] + ac[1]) + (ac[2] + ac[3]);
    __syncthreads();

    if (t < HT) {
        float s = 0.f;
        #pragma unroll
        for (int ic2 = 0; ic2 < 16; ++ic2)
            s += partial[ic2][t];
        const float denom = (float)(n1 * n2);
        const float pad = (float)(LL * LL) - denom;
        out[b * HH + h0 + t] = (s + pad * fmaxf(bias[h0 + t], 0.f)) / denom;
    }
}

extern "C" void kernel_launch(void* const* d_in, const int* in_sizes, int n_in,
                              void* d_out, int out_size, void* d_ws, size_t ws_size,
                              hipStream_t stream) {
    const float* x1 = (const float*)d_in[0];
    const int*   s1 = (const int*)d_in[1];
    const float* x2 = (const float*)d_in[2];
    const int*   s2 = (const int*)d_in[3];
    const float* W  = (const float*)d_in[4];
    const float* b  = (const float*)d_in[5];
    float* out = (float*)d_out;
    (void)d_ws; (void)ws_size;

    fused_kernel<<<dim3(BB, HH / HT), 256, 0, stream>>>(x1, x2, W, s1, s2, b, out);
}

// Round 6
// 74.248 us; speedup vs baseline: 1.1997x; 1.1997x over previous
//
#include <hip/hip_runtime.h>

// Problem constants: B=32, L1=L2=64, DIM_HID=256, FEAT=512
#define BB 32
#define LL 64
#define HH 256
#define FF 512
#define WSTRIDE 1024   // W is [256, 1024] row-major
#define HT 16          // h-tile per block: 512 blocks = 2/CU
#define BK 128         // K-tile (4 iterations over K=512)
#define NKT (FF / BK)
#define YSTR 17        // f32 y-tile stride (16 + 1 pad)

#define NX1 (BB * LL * FF)          // 1,048,576 shorts (x1)
#define NX  (2 * NX1)               // x1+x2
#define NW  (HH * WSTRIDE)          // 262,144 shorts (W)
#define NTOT (NX + NW)

// LDS tile geometry (in shorts). Rows are 128 shorts = 256 B, NO pad
// (global_load_lds needs linear dest); bank conflicts handled by the
// (row&7)<<3 short-index XOR swizzle, pre-applied in the workspace.
#define ATILE_SH 8192              // 64 rows * 128
#define BTILE_SH 2048              // 16 rows * 128
#define BUF_SH   (2 * ATILE_SH + 2 * BTILE_SH)   // 20480 shorts = 40960 B

typedef float float4v __attribute__((ext_vector_type(4)));
typedef short short8  __attribute__((ext_vector_type(8)));

// Packed fp32x2 -> bf16x2 (RNE in HW). No builtin on gfx950 -> inline asm.
static __device__ __forceinline__ unsigned int cvt_pk_bf16(float lo, float hi) {
    unsigned int r;
    asm("v_cvt_pk_bf16_f32 %0, %1, %2" : "=v"(r) : "v"(lo), "v"(hi));
    return r;
}

// Async global -> LDS, 16 B per lane. LDS dest = wave-uniform base + lane*16.
static __device__ __forceinline__ void gl16(const unsigned short* g, unsigned short* l) {
    __builtin_amdgcn_global_load_lds(
        (const __attribute__((address_space(1))) void*)(const void*)g,
        (__attribute__((address_space(3))) void*)(void*)l,
        16, 0, 0);
}

// ---------------- Kernel 1: fp32 -> bf16 pre-convert, PRE-SWIZZLED ----------------
// Swizzle: within each 128-short (256B) row-block, short index ^= (row&7)<<3.
// x rows are 512 shorts (row index = idx>>9); W rows are 1024 shorts (idx>>10).
// Fused kernel's staging is then a pure linear copy (global_load_lds) while
// fragment ds_read_b128s apply the same XOR -> 2-way banks (free, m136).
__global__ __launch_bounds__(256)
void convert_kernel(const float* __restrict__ x1,
                    const float* __restrict__ x2,
                    const float* __restrict__ W,
                    unsigned short* __restrict__ xb,
                    unsigned short* __restrict__ Wb) {
    const int idx = (blockIdx.x * 256 + threadIdx.x) * 8;
    const float* src;
    unsigned short* dst;
    if (idx < NX) {
        src = (idx < NX1) ? (x1 + idx) : (x2 + (idx - NX1));
        const int r7 = (idx >> 9) & 7;          // L-row & 7 (NX1 is row-aligned)
        dst = xb + (idx ^ (r7 << 3));
    } else {
        const int rel = idx - NX;
        src = W + rel;
        const int r7 = (rel >> 10) & 7;         // h-row & 7
        dst = Wb + (rel ^ (r7 << 3));
    }
    const float4 f0 = *(const float4*)src;
    const float4 f1 = *(const float4*)(src + 4);
    union { short8 s; unsigned int u[4]; } o;
    o.u[0] = cvt_pk_bf16(f0.x, f0.y);
    o.u[1] = cvt_pk_bf16(f0.z, f0.w);
    o.u[2] = cvt_pk_bf16(f1.x, f1.y);
    o.u[3] = cvt_pk_bf16(f1.z, f1.w);
    *(short8*)dst = o.s;
}

// ---------------- Kernel 2: fused bf16 MFMA GEMM + masked pair relu-sum ----------------
// One block per (batch b, h-tile of 16). 512 blocks = 2/CU (80 KB LDS each).
// 2-deep prefetch pipeline with COUNTED vmcnt (T4): issue tile kt+2 into the
// buffer just freed by barrier-1, then s_waitcnt vmcnt(10) (tile kt+1's own
// loads done, kt+2's 10 still in flight) + raw s_barrier. Never a full
// vmcnt(0) drain in the steady loop. sched_barrier(0) fences per rule #18.
__global__ __launch_bounds__(256)
void fused_kernel(const unsigned short* __restrict__ xb,
                  const unsigned short* __restrict__ Wb,
                  const int* __restrict__ s1p,
                  const int* __restrict__ s2p,
                  const float* __restrict__ bias,
                  float* __restrict__ out) {
    const int b  = blockIdx.x;
    const int h0 = blockIdx.y * HT;

    __shared__ __align__(16) unsigned short smem[2 * BUF_SH];   // 81920 B
    // epilogue overlay on buffer 0 (disjoint from buf1, which the last
    // K-step reads -> no barrier needed between last MFMA and overlay write)
    float (*y1t)[YSTR]     = (float (*)[YSTR])(smem);
    float (*y2t)[YSTR]     = (float (*)[YSTR])((char*)smem + 4352);
    float (*partial)[YSTR] = (float (*)[YSTR])((char*)smem + 8704);

    const int t      = threadIdx.x;
    const int lane   = t & 63;
    const int wid    = t >> 6;          // 0..3
    const int srcSel = wid >> 1;        // 0: y1, 1: y2
    const int mrow   = (wid & 1) * 32;  // wave's 32-row half
    const int lm     = lane & 15;
    const int quad   = lane >> 4;

    // staging coords: thread covers 16B at (row = base + t>>4, col shorts = (t&15)*8)
    const int srow = t >> 4;            // 0..15
    const int scol = (t & 15) * 8;

    const unsigned short* a1base = xb +       (size_t)(b * LL + srow) * FF + scol;
    const unsigned short* a2base = xb + NX1 + (size_t)(b * LL + srow) * FF + scol;
    const unsigned short* w1base = Wb + (size_t)(h0 + srow) * WSTRIDE + scol;
    const unsigned short* w2base = w1base + FF;

    float4v acc[2];
    acc[0] = (float4v){0.f, 0.f, 0.f, 0.f};
    acc[1] = (float4v){0.f, 0.f, 0.f, 0.f};

    // fragment read setup. Logical in-tile offset R*128 + quad*8 + ks*32 is
    // stored at physical (R*128 + ((quad*8 + ks*32) ^ ((R&7)<<3))). Since the
    // two fields are bit-disjoint: = R*128 + (quad*8 ^ x18) + (ks*32 ^ x20).
    const int xm  = (lm & 7) << 3;      // (row&7)<<3 — same for all our rows
    const int qb  = (quad * 8) ^ (xm & 0x18);
    const int x20 = xm & 0x20;

    // issue one K-tile's staging (10 global_load_lds per thread = 10 vmcnt/wave)
    auto issue = [&](int kt, int bsel) {
        unsigned short* Lb = smem + bsel * BUF_SH;
        const int ko = kt * BK;
        #pragma unroll
        for (int q = 0; q < 4; ++q) {
            gl16(a1base + (size_t)q * (16 * FF) + ko, Lb + q * 2048 + wid * 512);
            gl16(a2base + (size_t)q * (16 * FF) + ko, Lb + ATILE_SH + q * 2048 + wid * 512);
        }
        gl16(w1base + ko, Lb + 2 * ATILE_SH + wid * 512);
        gl16(w2base + ko, Lb + 2 * ATILE_SH + BTILE_SH + wid * 512);
    };

    // prologue: fill both buffers; wait only tile 0 (tile 1 stays in flight)
    issue(0, 0);
    issue(1, 1);
    asm volatile("s_waitcnt vmcnt(10)" ::: "memory");
    __builtin_amdgcn_s_barrier();
    __builtin_amdgcn_sched_barrier(0);

    #pragma unroll
    for (int kt = 0; kt < NKT; ++kt) {
        const unsigned short* Lb = smem + (kt & 1) * BUF_SH;
        const unsigned short* A  = Lb + (srcSel ? ATILE_SH : 0);
        const unsigned short* Bt = Lb + 2 * ATILE_SH + (srcSel ? BTILE_SH : 0);
        const unsigned short* pA0 = A + (mrow + lm) * 128 + qb;
        const unsigned short* pA1 = pA0 + 16 * 128;
        const unsigned short* pB  = Bt + lm * 128 + qb;

        #pragma unroll
        for (int ks = 0; ks < 4; ++ks) {
            const int kof = (ks * 32) ^ x20;
            const short8 a0 = *(const short8*)(pA0 + kof);
            const short8 a1 = *(const short8*)(pA1 + kof);
            const short8 b0 = *(const short8*)(pB + kof);
            acc[0] = __builtin_amdgcn_mfma_f32_16x16x32_bf16(a0, b0, acc[0], 0, 0, 0);
            acc[1] = __builtin_amdgcn_mfma_f32_16x16x32_bf16(a1, b0, acc[1], 0, 0, 0);
        }

        if (kt + 2 < NKT) {
            // barrier-1: all waves done reading buf kt&1 -> safe to overwrite
            __builtin_amdgcn_sched_barrier(0);
            __builtin_amdgcn_s_barrier();
            issue(kt + 2, kt & 1);
            // wait own tile kt+1 loads (10 of kt+2's stay outstanding)
            asm volatile("s_waitcnt vmcnt(10)" ::: "memory");
            __builtin_amdgcn_s_barrier();   // all waves' tile kt+1 resident
            __builtin_amdgcn_sched_barrier(0);
        } else if (kt + 1 < NKT) {
            // no more issues: just certify tile kt+1 fully resident
            __builtin_amdgcn_sched_barrier(0);
            asm volatile("s_waitcnt vmcnt(0)" ::: "memory");
            __builtin_amdgcn_s_barrier();
            __builtin_amdgcn_sched_barrier(0);
        }
        // kt == NKT-1: fall through to epilogue (overlay targets buf0 region,
        // disjoint from buf1 which this step read; sync via the epilogue barrier)
    }

    // epilogue -> LDS y-tiles (overlay); fold bias into y2'
    // C/D layout: col = lane&15, row = quad*4 + j (m89-verified)
    {
        float (*yt)[YSTR] = srcSel ? y2t : y1t;
        const float bv = srcSel ? bias[h0 + lm] : 0.0f;
        #pragma unroll
        for (int im = 0; im < 2; ++im)
            #pragma unroll
            for (int j = 0; j < 4; ++j)
                yt[mrow + im * 16 + quad * 4 + j][lm] = acc[im][j] + bv;
    }
    __syncthreads();

    // masked pair relu-sum: thread = (h in 0..15, i-chunk of 4)
    const int n1 = s1p[b];
    const int n2 = s2p[b];
    const int h  = t & 15;
    const int ic = t >> 4;   // 0..15

    float r1[4];
    #pragma unroll
    for (int ii = 0; ii < 4; ++ii) {
        const int i = ic * 4 + ii;
        r1[ii] = (i < n1) ? y1t[i][h] : -1e30f;  // invalid i -> relu gives 0
    }

    float ac[4] = {0.f, 0.f, 0.f, 0.f};
    int j = 0;
    for (; j + 4 <= n2; j += 4) {
        const float v0 = y2t[j][h];
        const float v1 = y2t[j + 1][h];
        const float v2 = y2t[j + 2][h];
        const float v3 = y2t[j + 3][h];
        #pragma unroll
        for (int ii = 0; ii < 4; ++ii) {
            ac[ii] += fmaxf(r1[ii] + v0, 0.f);
            ac[ii] += fmaxf(r1[ii] + v1, 0.f);
            ac[ii] += fmaxf(r1[ii] + v2, 0.f);
            ac[ii] += fmaxf(r1[ii] + v3, 0.f);
        }
    }
    for (; j < n2; ++j) {
        const float v0 = y2t[j][h];
        #pragma unroll
        for (int ii = 0; ii < 4; ++ii)
            ac[ii] += fmaxf(r1[ii] + v0, 0.f);
    }
    partial[ic][h] = (ac[0] + ac[1]) + (ac[2] + ac[3]);
    __syncthreads();

    if (t < HT) {
        float s = 0.f;
        #pragma unroll
        for (int ic2 = 0; ic2 < 16; ++ic2)
            s += partial[ic2][t];
        const float denom = (float)(n1 * n2);
        const float pad = (float)(LL * LL) - denom;
        out[b * HH + h0 + t] = (s + pad * fmaxf(bias[h0 + t], 0.f)) / denom;
    }
}

extern "C" void kernel_launch(void* const* d_in, const int* in_sizes, int n_in,
                              void* d_out, int out_size, void* d_ws, size_t ws_size,
                              hipStream_t stream) {
    const float* x1 = (const float*)d_in[0];
    const int*   s1 = (const int*)d_in[1];
    const float* x2 = (const float*)d_in[2];
    const int*   s2 = (const int*)d_in[3];
    const float* W  = (const float*)d_in[4];
    const float* b  = (const float*)d_in[5];
    float* out = (float*)d_out;

    unsigned short* xb = (unsigned short*)d_ws;   // x1,x2 bf16, pre-swizzled
    unsigned short* Wb = xb + NX;                 // W bf16, pre-swizzled

    convert_kernel<<<NTOT / (256 * 8), 256, 0, stream>>>(x1, x2, W, xb, Wb);
    fused_kernel<<<dim3(BB, HH / HT), 256, 0, stream>>>(xb, Wb, s1, s2, b, out);
}